// Round 1
// baseline (195.993 us; speedup 1.0000x reference)
//
#include <hip/hip_runtime.h>
#include <hip/hip_cooperative_groups.h>

namespace cg = cooperative_groups;

#define B 8
#define N 2048
#define D 1024
#define C 64           // chunks along i
#define LC (N / C)     // 32
#define M 6            // Taylor terms; |c_j*k_i| <~ 0.2 -> err ~1e-7
#define PB 96          // scan blocks: B*M*D/4 / 128 (old) ; B*M*D/2 / 256 (fused)
#define GRID 1024      // B*C*2
#define TPB 256

// ===========================================================================
// Fused cooperative kernel: P0 proj -> P1 partials (f->regs) -> P2 scans ->
// P3 output. f is read exactly once; 3 grid syncs replace 3 kernel launches.
// __launch_bounds__(256,4): VGPR<=128 -> 4 blocks/CU -> 1024 blocks resident.
__global__ __launch_bounds__(TPB, 4) void k_fused(
    const float* __restrict__ x, const float* __restrict__ f,
    const float* __restrict__ wk, const float* __restrict__ wq,
    float* __restrict__ kq, float* __restrict__ Tc,
    float* __restrict__ part, float* __restrict__ out)
{
    cg::grid_group grid = cg::this_grid();
    const int tid  = threadIdx.x;
    const int blk  = blockIdx.x;
    const int lane = tid & 63;

    __shared__ float sk[LC];
    __shared__ float sq[LC];

    // ------------------------------------------------------------ P0: k,q
    {
        const int wave = (blk << 2) | (tid >> 6);          // 0..4095
        const float4* wk4 = (const float4*)wk;
        const float4* wq4 = (const float4*)wq;
        float4 kw[4], qw[4];
#pragma unroll
        for (int t = 0; t < 4; ++t) { kw[t] = wk4[t * 64 + lane]; qw[t] = wq4[t * 64 + lane]; }
#pragma unroll
        for (int r = 0; r < 4; ++r) {
            const int row = (wave << 2) | r;               // 4 rows per wave
            const float4* xr = (const float4*)(x + (size_t)row * D);
            float ak = 0.f, aq = 0.f;
#pragma unroll
            for (int t = 0; t < 4; ++t) {
                float4 xv = xr[t * 64 + lane];
                ak += xv.x * kw[t].x + xv.y * kw[t].y + xv.z * kw[t].z + xv.w * kw[t].w;
                aq += xv.x * qw[t].x + xv.y * qw[t].y + xv.z * qw[t].z + xv.w * qw[t].w;
            }
#pragma unroll
            for (int off = 32; off > 0; off >>= 1) {
                ak += __shfl_down(ak, off, 64);
                aq += __shfl_down(aq, off, 64);
            }
            if (lane == 0) { kq[row] = ak; kq[B * N + row] = aq; }
        }
    }
    __threadfence();
    grid.sync();

    // ------------------------------------------------------------ P1: partials
    const int dhalf = blk & 1;
    const int c     = (blk >> 1) & (C - 1);
    const int b     = blk >> 7;
    const int d     = dhalf * 512 + tid * 2;               // thread owns 2 d-cols

    if (tid < LC)                        sk[tid]      = kq[b * N + c * LC + tid];
    else if (tid >= 64 && tid < 64 + LC) sq[tid - 64] = kq[B * N + b * N + c * LC + (tid - 64)];
    __syncthreads();

    const float2* fb = (const float2*)(f + (size_t)(b * N + c * LC) * D + d);
    float2 freg[LC];                                       // 64 VGPRs: f-tile
    float2 s[M];
#pragma unroll
    for (int m = 0; m < M; ++m) s[m] = make_float2(0.f, 0.f);
#pragma unroll
    for (int i = 0; i < LC; ++i) {                         // MUST fully unroll (freg idx)
        float2 ff = fb[i * (D / 2)];
        freg[i] = ff;
        float kk = sk[i];
        float w  = (kk != 0.0f) ? 1.0f : 0.0f;
        s[0].x += w * ff.x; s[0].y += w * ff.y;
        float kp = kk;
#pragma unroll
        for (int m = 1; m < M; ++m) {
            s[m].x += kp * ff.x; s[m].y += kp * ff.y;
            kp *= kk;
        }
    }
    {
        float2* pw = (float2*)(part + ((size_t)(b * C + c) * M) * D + d);
#pragma unroll
        for (int m = 0; m < M; ++m) pw[m * (D / 2)] = s[m];
    }
    __threadfence();
    grid.sync();

    // ------------------------------------------------------------ P2: scans
    if (blk < PB) {
        // exclusive scan of part over c; thread per (b,m,d2) float2 column
        const int gid = blk * TPB + tid;                   // < 24576 = B*M*D/2
        const int d2  = gid & (D / 2 - 1);
        const int m   = (gid >> 9) % M;
        const int bb  = (gid >> 9) / M;
        float2* p2 = (float2*)part;
        const size_t base = ((size_t)bb * C * M + m) * (D / 2) + d2;
        const size_t cs   = (size_t)M * (D / 2);
        float2 run = make_float2(0.f, 0.f);
#pragma unroll 1
        for (int c0 = 0; c0 < C; c0 += 8) {
            float2 buf[8];
#pragma unroll
            for (int j = 0; j < 8; ++j) buf[j] = p2[base + (size_t)(c0 + j) * cs];
#pragma unroll
            for (int j = 0; j < 8; ++j) {
                float2 v = buf[j];
                p2[base + (size_t)(c0 + j) * cs] = run;
                run.x += v.x; run.y += v.y;
            }
        }
    } else if (blk < PB + 2) {
        // scanT: wave per batch; lane = chunk index
        const int b2 = ((blk - PB) << 2) | (tid >> 6);     // 0..7
        float tm[M] = {0.f, 0.f, 0.f, 0.f, 0.f, 0.f};
        const float* kb = kq + b2 * N + lane * LC;
#pragma unroll
        for (int i = 0; i < LC; ++i) {
            float kk = kb[i];
            tm[0] += (kk != 0.0f) ? 1.0f : 0.0f;
            float kp = kk;
#pragma unroll
            for (int m = 1; m < M; ++m) { tm[m] += kp; kp *= kk; }
        }
#pragma unroll
        for (int m = 0; m < M; ++m) {
            float v = tm[m];
            const float orig = v;
#pragma unroll
            for (int off = 1; off < 64; off <<= 1) {
                float nv = __shfl_up(v, off, 64);
                if (lane >= off) v += nv;
            }
            Tc[(b2 * C + lane) * M + m] = v - orig;        // exclusive prefix
        }
    }
    __threadfence();
    grid.sync();

    // ------------------------------------------------------------ P3: output
    {
        float2 s2[M];
        const float2* pr = (const float2*)(part + ((size_t)(b * C + c) * M) * D + d);
#pragma unroll
        for (int m = 0; m < M; ++m) s2[m] = pr[m * (D / 2)];
        float t[M];
#pragma unroll
        for (int m = 0; m < M; ++m) t[m] = Tc[(b * C + c) * M + m];

        float2* ob = (float2*)(out + (size_t)(b * N + c * LC) * D + d);
#pragma unroll
        for (int i = 0; i < LC; ++i) {                     // MUST fully unroll (freg idx)
            float2 ff = freg[i];
            float kk = sk[i];
            float qq = sq[i];
            float w  = (kk != 0.0f) ? 1.0f : 0.0f;
            t[0] += w;
            s2[0].x += w * ff.x; s2[0].y += w * ff.y;
            float kp = kk;
#pragma unroll
            for (int m = 1; m < M; ++m) {
                t[m] += kp;
                s2[m].x += kp * ff.x; s2[m].y += kp * ff.y;
                kp *= kk;
            }
            const float cj = qq * 0.03125f;
            const float g2 = cj * 0.5f;
            const float g3 = cj * (1.0f / 3.0f);
            const float g4 = cj * 0.25f;
            const float g5 = cj * 0.2f;
            float Z = ((((t[5] * g5 + t[4]) * g4 + t[3]) * g3 + t[2]) * g2 + t[1]) * cj + t[0];
            float rz = __builtin_amdgcn_rcpf(Z);
            float2 o;
            o.x = (((((s2[5].x * g5 + s2[4].x) * g4 + s2[3].x) * g3 + s2[2].x) * g2 + s2[1].x) * cj + s2[0].x) * rz;
            o.y = (((((s2[5].y * g5 + s2[4].y) * g4 + s2[3].y) * g3 + s2[2].y) * g2 + s2[1].y) * cj + s2[0].y) * rz;
            ob[i * (D / 2)] = o;
        }
    }
}

// ===========================================================================
// Fallback path: the proven 4-kernel pipeline (used only if the fused kernel
// cannot reach 4 blocks/CU co-residency, e.g. unexpected register growth).
__global__ __launch_bounds__(256) void k_proj(const float* __restrict__ x,
                                              const float* __restrict__ wk,
                                              const float* __restrict__ wq,
                                              float* __restrict__ kq) {
    const int wave = threadIdx.x >> 6;
    const int lane = threadIdx.x & 63;
    const int row  = blockIdx.x * 4 + wave;
    const float4* xr  = (const float4*)(x + (size_t)row * D);
    const float4* wk4 = (const float4*)wk;
    const float4* wq4 = (const float4*)wq;
    float ak = 0.f, aq = 0.f;
#pragma unroll
    for (int t = 0; t < (D / 4) / 64; ++t) {
        float4 xv = xr[t * 64 + lane];
        float4 kv = wk4[t * 64 + lane];
        float4 qv = wq4[t * 64 + lane];
        ak += xv.x * kv.x + xv.y * kv.y + xv.z * kv.z + xv.w * kv.w;
        aq += xv.x * qv.x + xv.y * qv.y + xv.z * qv.z + xv.w * qv.w;
    }
#pragma unroll
    for (int off = 32; off > 0; off >>= 1) {
        ak += __shfl_down(ak, off, 64);
        aq += __shfl_down(aq, off, 64);
    }
    if (lane == 0) { kq[row] = ak; kq[B * N + row] = aq; }
}

__global__ __launch_bounds__(128) void k_partial(const float* __restrict__ kq,
                                                 const float* __restrict__ f,
                                                 float* __restrict__ part) {
    const int dhalf = blockIdx.x & 1;
    const int c     = (blockIdx.x >> 1) & (C - 1);
    const int b     = blockIdx.x >> 7;
    const int d     = dhalf * 512 + threadIdx.x * 4;
    const float*  kb = kq + b * N + c * LC;
    const float4* fb = (const float4*)(f + (size_t)(b * N + c * LC) * D + d);
    float4 s[M];
#pragma unroll
    for (int m = 0; m < M; ++m) s[m] = make_float4(0.f, 0.f, 0.f, 0.f);
#pragma unroll 8
    for (int i = 0; i < LC; ++i) {
        float4 ff = fb[i * (D / 4)];
        float  kk = kb[i];
        float  w  = (kk != 0.0f) ? 1.0f : 0.0f;
        s[0].x += w * ff.x; s[0].y += w * ff.y; s[0].z += w * ff.z; s[0].w += w * ff.w;
        float kp = kk;
#pragma unroll
        for (int m = 1; m < M; ++m) {
            s[m].x += kp * ff.x; s[m].y += kp * ff.y;
            s[m].z += kp * ff.z; s[m].w += kp * ff.w;
            kp *= kk;
        }
    }
    float4* pb = (float4*)(part + ((size_t)(b * C + c) * M) * D + d);
#pragma unroll
    for (int m = 0; m < M; ++m) pb[m * (D / 4)] = s[m];
}

__global__ __launch_bounds__(128) void k_scan(const float* __restrict__ kq,
                                              float* __restrict__ Tc,
                                              float* __restrict__ part) {
    if (blockIdx.x < PB) {
        const int gid = blockIdx.x * 128 + threadIdx.x;
        const int d4  = gid & (D / 4 - 1);
        const int m   = (gid >> 8) % M;
        const int b   = gid / (256 * M);
        float4* p4 = (float4*)part;
        const size_t base = ((size_t)b * C * M + m) * (D / 4) + d4;
        const size_t cs   = (size_t)M * (D / 4);
        float4 run = make_float4(0.f, 0.f, 0.f, 0.f);
#pragma unroll 1
        for (int c0 = 0; c0 < C; c0 += 8) {
            float4 buf[8];
#pragma unroll
            for (int j = 0; j < 8; ++j) buf[j] = p4[base + (size_t)(c0 + j) * cs];
#pragma unroll
            for (int j = 0; j < 8; ++j) {
                float4 v = buf[j];
                p4[base + (size_t)(c0 + j) * cs] = run;
                run.x += v.x; run.y += v.y; run.z += v.z; run.w += v.w;
            }
        }
    } else {
        const int b2   = blockIdx.x - PB;
        const int lane = threadIdx.x;
        if (lane < 64) {
            float tm[M] = {0.f, 0.f, 0.f, 0.f, 0.f, 0.f};
            const float* kb = kq + b2 * N + lane * LC;
#pragma unroll
            for (int i = 0; i < LC; ++i) {
                float kk = kb[i];
                tm[0] += (kk != 0.0f) ? 1.0f : 0.0f;
                float kp = kk;
#pragma unroll
                for (int m = 1; m < M; ++m) { tm[m] += kp; kp *= kk; }
            }
#pragma unroll
            for (int m = 0; m < M; ++m) {
                float v = tm[m];
                const float orig = v;
#pragma unroll
                for (int off = 1; off < 64; off <<= 1) {
                    float nv = __shfl_up(v, off, 64);
                    if (lane >= off) v += nv;
                }
                Tc[(b2 * C + lane) * M + m] = v - orig;
            }
        }
    }
}

__global__ __launch_bounds__(128) void k_out(const float* __restrict__ kq,
                                             const float* __restrict__ f,
                                             const float* __restrict__ Tc,
                                             const float* __restrict__ part,
                                             float* __restrict__ out) {
    const int dhalf = blockIdx.x & 1;
    const int c     = (blockIdx.x >> 1) & (C - 1);
    const int b     = blockIdx.x >> 7;
    const int d     = dhalf * 512 + threadIdx.x * 4;

    float4 s[M];
    float  t[M];
    const float4* pb = (const float4*)(part + ((size_t)(b * C + c) * M) * D + d);
#pragma unroll
    for (int m = 0; m < M; ++m) s[m] = pb[m * (D / 4)];
#pragma unroll
    for (int m = 0; m < M; ++m) t[m] = Tc[(b * C + c) * M + m];

    const float*  kb = kq + b * N + c * LC;
    const float*  qb = kq + B * N + b * N + c * LC;
    const float4* fb = (const float4*)(f + (size_t)(b * N + c * LC) * D + d);
    float4*       ob = (float4*)(out + (size_t)(b * N + c * LC) * D + d);

#pragma unroll 4
    for (int i = 0; i < LC; ++i) {
        float4 ff = fb[i * (D / 4)];
        float  kk = kb[i];
        float  qq = qb[i];
        float  w  = (kk != 0.0f) ? 1.0f : 0.0f;
        t[0] += w;
        s[0].x += w * ff.x; s[0].y += w * ff.y; s[0].z += w * ff.z; s[0].w += w * ff.w;
        float kp = kk;
#pragma unroll
        for (int m = 1; m < M; ++m) {
            t[m] += kp;
            s[m].x += kp * ff.x; s[m].y += kp * ff.y;
            s[m].z += kp * ff.z; s[m].w += kp * ff.w;
            kp *= kk;
        }
        const float cj = qq * 0.03125f;
        const float g2 = cj * 0.5f;
        const float g3 = cj * (1.0f / 3.0f);
        const float g4 = cj * 0.25f;
        const float g5 = cj * 0.2f;
        float Z = ((((t[5] * g5 + t[4]) * g4 + t[3]) * g3 + t[2]) * g2 + t[1]) * cj + t[0];
        float rz = __builtin_amdgcn_rcpf(Z);
        float4 o;
        o.x = (((((s[5].x * g5 + s[4].x) * g4 + s[3].x) * g3 + s[2].x) * g2 + s[1].x) * cj + s[0].x) * rz;
        o.y = (((((s[5].y * g5 + s[4].y) * g4 + s[3].y) * g3 + s[2].y) * g2 + s[1].y) * cj + s[0].y) * rz;
        o.z = (((((s[5].z * g5 + s[4].z) * g4 + s[3].z) * g3 + s[2].z) * g2 + s[1].z) * cj + s[0].z) * rz;
        o.w = (((((s[5].w * g5 + s[4].w) * g4 + s[3].w) * g3 + s[2].w) * g2 + s[1].w) * cj + s[0].w) * rz;
        ob[i * (D / 4)] = o;
    }
}

// ===========================================================================
extern "C" void kernel_launch(void* const* d_in, const int* in_sizes, int n_in,
                              void* d_out, int out_size, void* d_ws, size_t ws_size,
                              hipStream_t stream) {
    (void)in_sizes; (void)n_in; (void)out_size; (void)ws_size;
    const float* x  = (const float*)d_in[0];
    const float* f  = (const float*)d_in[1];
    const float* wk = (const float*)d_in[2];
    const float* wq = (const float*)d_in[3];
    float* out = (float*)d_out;
    float* ws  = (float*)d_ws;

    float* kq   = ws;                        // 2*B*N   = 32768 floats
    float* Tc   = ws + 2 * B * N;            // B*C*M   = 3072 floats
    float* part = ws + 2 * B * N + 4096;     // B*C*M*D = 3145728 floats (~12.6 MB)

    // host-side co-residency check (memoized; pure host call, capture-safe)
    static int coop_ok = -1;
    if (coop_ok < 0) {
        int nb = 0;
        hipError_t e = hipOccupancyMaxActiveBlocksPerMultiprocessor(
            &nb, (const void*)k_fused, TPB, 0);
        coop_ok = (e == hipSuccess && nb >= (GRID + 255) / 256) ? 1 : 0;  // need 4/CU
    }

    hipError_t le = hipErrorUnknown;
    if (coop_ok) {
        void* args[] = {(void*)&x, (void*)&f, (void*)&wk, (void*)&wq,
                        (void*)&kq, (void*)&Tc, (void*)&part, (void*)&out};
        le = hipLaunchCooperativeKernel((const void*)k_fused, dim3(GRID), dim3(TPB),
                                        args, 0, stream);
    }
    if (!coop_ok || le != hipSuccess) {
        hipLaunchKernelGGL(k_proj,    dim3(B * N / 4), dim3(256), 0, stream, x, wk, wq, kq);
        hipLaunchKernelGGL(k_partial, dim3(B * C * 2), dim3(128), 0, stream, kq, f, part);
        hipLaunchKernelGGL(k_scan,    dim3(PB + B),    dim3(128), 0, stream, kq, Tc, part);
        hipLaunchKernelGGL(k_out,     dim3(B * C * 2), dim3(128), 0, stream, kq, f, Tc, part, out);
    }
}